// Round 1
// baseline (646.705 us; speedup 1.0000x reference)
//
#include <hip/hip_runtime.h>

#define HW 96
#define NPIX 9216      // 96*96
#define NCH 128
#define NB 16
#define HP 98          // haloed plane dim (coords -1..96)

// ---------------- channel mix: mixed[b,c,p] = sum_i lin[c,i] * x[b,i,p] ----------------
// No-LDS GEMM. Block = 512 thr (8 waves), tile = 128 px x 128 ch, thread = 2 px,
// wave = 16 ch (lin wave-uniform -> s_load_dwordx8 into SGPRs, the 1 allowed
// SGPR operand of v_fma).
// R6: explicit ping-pong double-buffer on the x loads. R5's single-buffer loop
// drained vmcnt before each 256-FMA block (VALUBusy 51% at 44% of the fp32 FMA
// roofline). Issuing the next 8-k batch before consuming the current one keeps
// 8 loads (64B/lane) in flight under every FMA block -> compiler emits
// s_waitcnt vmcnt(8), not a full drain. +16 VGPR (~76 total), still >=5 waves/SIMD.
template<int K>
__global__ __launch_bounds__(512, 4) void mix_kernel(const float* __restrict__ x,
                                                     const float* __restrict__ lin,
                                                     float* __restrict__ mixed) {
    const int b    = blockIdx.y;
    const int lane = threadIdx.x & 63;
    const int p    = blockIdx.x * 128 + lane * 2;
    const int c0   = __builtin_amdgcn_readfirstlane((threadIdx.x >> 6) * 16);
    const float* xb = x + (size_t)b * K * NPIX + p;
    const float* lr = lin + c0 * K;

    float2 acc[16];
    #pragma unroll
    for (int c = 0; c < 16; ++c) acc[c] = float2{0.f, 0.f};

    float2 va[8], vb[8];

#define MIX_LOAD(buf, k0)                                         \
    _Pragma("unroll")                                             \
    for (int j = 0; j < 8; ++j)                                   \
        buf[j] = *(const float2*)&xb[(size_t)((k0) + j) * NPIX];

#define MIX_FMA(buf, k0)                                          \
    _Pragma("unroll")                                             \
    for (int c = 0; c < 16; ++c) {                                \
        const float* lc = lr + c * K + (k0);                      \
        _Pragma("unroll")                                         \
        for (int j = 0; j < 8; ++j) {                             \
            acc[c].x = fmaf(lc[j], buf[j].x, acc[c].x);           \
            acc[c].y = fmaf(lc[j], buf[j].y, acc[c].y);           \
        }                                                         \
    }

    MIX_LOAD(va, 0);
    for (int k0 = 0; k0 < K - 16; k0 += 16) {
        MIX_LOAD(vb, k0 + 8);     // prefetch batch k0+8 (in flight during FMA below)
        MIX_FMA(va, k0);
        MIX_LOAD(va, k0 + 16);    // prefetch batch k0+16
        MIX_FMA(vb, k0 + 8);
    }
    MIX_LOAD(vb, K - 8);
    MIX_FMA(va, K - 16);
    MIX_FMA(vb, K - 8);
#undef MIX_LOAD
#undef MIX_FMA

    float* ob = mixed + (size_t)b * NCH * NPIX + p;
    #pragma unroll
    for (int c = 0; c < 16; ++c)
        *(float2*)&ob[(size_t)(c0 + c) * NPIX] = acc[c];
}

__device__ inline float clamp01(float z) { return fminf(fmaxf(z, 0.f), 1.f); }

// ---------------- bilinear affine sample (zero-halo LDS plane) ----------------
// Plane staged into LDS with a 1px zero border (coords -1..96). ix clamped to
// [-1,96]: every out-of-range tap then reads a zero cell with the correct
// weight, eliminating all validity masks. Box-sample-of-ones factorizes:
// bw = min(clamp01(bx+1), clamp01(96-bx)) * (same in y). 2-lerp form = 6 FMA.
// R6: 384 -> 512 threads. LDS (38.4 KB) still allows 4 blocks/CU, so waves/CU
// rises 24 -> 32 for this BW-bound kernel; grid 2048 = exactly 2 rounds of
// 4 blocks/CU.
template<bool RES, bool POOL>
__global__ __launch_bounds__(512) void sample_kernel(const float* __restrict__ mixed,
                                                     const float* __restrict__ geo,
                                                     const float* __restrict__ box,
                                                     float* __restrict__ out,
                                                     float* __restrict__ pooled) {
    __shared__ float m[HP * HP];           // 38.4 KB -> 4 blocks/CU, 32 waves/CU
    const int c = blockIdx.x;
    const int b = blockIdx.y;
    const int t = threadIdx.x;
    // zero only the halo border (interior is fully overwritten by the fill)
    if (t < HP) {                           // top & bottom rows
        m[t] = 0.f;
        m[(HP - 1) * HP + t] = 0.f;
    } else if (t < HP + 96) {               // left & right columns (rows 1..96)
        const int h = t - HP + 1;
        m[h * HP] = 0.f;
        m[h * HP + HP - 1] = 0.f;
    }
    const float* src = mixed + ((size_t)b * NCH + c) * NPIX;
    #pragma unroll
    for (int r = 0; r < NPIX / 512; ++r) {
        const int idx = r * 512 + t;
        const int h = idx / 96, w = idx - (idx / 96) * 96;
        m[(h + 1) * HP + (w + 1)] = src[idx];
    }
    const float* gth = geo + c * 6;
    const float* bth = box + c * 6;
    const float g0 = gth[0], g1 = gth[1], g3 = gth[3], g4 = gth[4];
    const float gcx = 48.f * gth[2] - 47.5f * (g0 + g1) + 47.5f;
    const float gcy = 48.f * gth[5] - 47.5f * (g3 + g4) + 47.5f;
    const float b0 = bth[0], b1 = bth[1], b3 = bth[3], b4 = bth[4];
    const float bcx = 48.f * bth[2] - 47.5f * (b0 + b1) + 47.5f;
    const float bcy = 48.f * bth[5] - 47.5f * (b3 + b4) + 47.5f;
    float* o = out + ((size_t)b * NCH + c) * NPIX;
    __syncthreads();
    float psum = 0.f;
    #pragma unroll 6
    for (int r = 0; r < NPIX / 512; ++r) {
        const int p = r * 512 + t;
        const int h = p / 96, w = p - (p / 96) * 96;
        const float fw = (float)w, fh = (float)h;
        float ix = fmaf(g0, fw, fmaf(g1, fh, gcx));
        float iy = fmaf(g3, fw, fmaf(g4, fh, gcy));
        ix = fminf(fmaxf(ix, -1.f), 96.f);
        iy = fminf(fmaxf(iy, -1.f), 96.f);
        const float x0f = floorf(ix), y0f = floorf(iy);
        const float fx = ix - x0f, fy = iy - y0f;
        const int base = ((int)y0f + 1) * HP + ((int)x0f + 1);
        const float m00 = m[base],      m01 = m[base + 1];
        const float m10 = m[base + HP], m11 = m[base + HP + 1];
        const float mx0 = fmaf(fx, m01 - m00, m00);
        const float mx1 = fmaf(fx, m11 - m10, m10);
        float v = fmaf(fy, mx1 - mx0, mx0);
        const float bx = fmaf(b0, fw, fmaf(b1, fh, bcx));
        const float by = fmaf(b3, fw, fmaf(b4, fh, bcy));
        const float Xs = fminf(clamp01(bx + 1.f), clamp01(96.f - bx));
        const float Ys = fminf(clamp01(by + 1.f), clamp01(96.f - by));
        v *= Xs * Ys;
        if (RES) v += o[p];
        o[p] = v;
        if (POOL) psum += v;
    }
    if (POOL) {
        #pragma unroll
        for (int off = 32; off > 0; off >>= 1) psum += __shfl_down(psum, off, 64);
        __shared__ float red[8];
        if ((t & 63) == 0) red[t >> 6] = psum;
        __syncthreads();
        if (t == 0) {
            float s = 0.f;
            #pragma unroll
            for (int i = 0; i < 8; ++i) s += red[i];
            pooled[b * NCH + c] = s * (1.f / (float)NPIX);
        }
    }
}

// ---------------- mean pool (fallback when ws has no room for pooled) ----------------
__global__ __launch_bounds__(256) void pool_kernel(const float* __restrict__ feat,
                                                   float* __restrict__ pooled) {
    const int bc = blockIdx.x;           // b*128 + c
    const float4* f = (const float4*)(feat + (size_t)bc * NPIX);
    float s = 0.f;
    for (int i = threadIdx.x; i < NPIX / 4; i += 256) {
        const float4 v = f[i];
        s += (v.x + v.y) + (v.z + v.w);
    }
    #pragma unroll
    for (int off = 32; off > 0; off >>= 1) s += __shfl_down(s, off, 64);
    __shared__ float red[4];
    if ((threadIdx.x & 63) == 0) red[threadIdx.x >> 6] = s;
    __syncthreads();
    if (threadIdx.x == 0)
        pooled[bc] = (red[0] + red[1] + red[2] + red[3]) * (1.f / (float)NPIX);
}

// ---------------- dense: logits[b,n] = pooled[b,:] . W[n,:] + bias[n] ----------------
__global__ __launch_bounds__(256) void dense_kernel(const float* __restrict__ pooled,
                                                    const float* __restrict__ Wt,
                                                    const float* __restrict__ bias,
                                                    float* __restrict__ out) {
    const int idx = blockIdx.x * 256 + threadIdx.x;
    if (idx >= NB * 1000) return;
    const int b = idx / 1000, n = idx - b * 1000;
    float acc = bias[n];
    const float* p = pooled + b * NCH;
    const float* wr = Wt + n * NCH;
    #pragma unroll 4
    for (int c = 0; c < NCH; ++c) acc = fmaf(p[c], wr[c], acc);
    out[idx] = acc;
}

extern "C" void kernel_launch(void* const* d_in, const int* in_sizes, int n_in,
                              void* d_out, int out_size, void* d_ws, size_t ws_size,
                              hipStream_t stream) {
    const float* x       = (const float*)d_in[0];   // [16,64,96,96]
    const float* in_geo  = (const float*)d_in[1];   // [128,2,3]
    const float* in_box  = (const float*)d_in[2];   // [128,2,3]
    const float* in_lin  = (const float*)d_in[3];   // [128,64]
    const float* lay_geo = (const float*)d_in[4];   // [4,128,2,3]
    const float* lay_box = (const float*)d_in[5];   // [4,128,2,3]
    const float* lay_lin = (const float*)d_in[6];   // [4,128,128]
    const float* dense_w = (const float*)d_in[7];   // [1000,128]
    const float* dense_b = (const float*)d_in[8];   // [1000]

    float* out  = (float*)d_out;
    float* feat = out + NB * 1000;                  // [16,128,96,96] lives in d_out
    float* mixed = (float*)d_ws;                    // 75.5 MB scratch

    const size_t mixedFloats = (size_t)NB * NCH * NPIX;
    const bool fusedPool = ws_size >= (mixedFloats + NB * NCH) * sizeof(float);
    float* pooled = fusedPool ? (float*)d_ws + mixedFloats : (float*)d_ws;

    const dim3 mixGrid(NPIX / 128, NB);             // 72 x 16 = 1152 blocks of 512
    const dim3 smpGrid(NCH, NB);

    mix_kernel<64><<<mixGrid, 512, 0, stream>>>(x, in_lin, mixed);
    sample_kernel<false, false><<<smpGrid, 512, 0, stream>>>(mixed, in_geo, in_box, feat, pooled);
    for (int i = 0; i < 3; ++i) {
        mix_kernel<128><<<mixGrid, 512, 0, stream>>>(feat, lay_lin + i * NCH * NCH, mixed);
        sample_kernel<true, false><<<smpGrid, 512, 0, stream>>>(mixed, lay_geo + i * NCH * 6,
                                                                lay_box + i * NCH * 6, feat, pooled);
    }
    mix_kernel<128><<<mixGrid, 512, 0, stream>>>(feat, lay_lin + 3 * NCH * NCH, mixed);
    if (fusedPool) {
        sample_kernel<true, true><<<smpGrid, 512, 0, stream>>>(mixed, lay_geo + 3 * NCH * 6,
                                                               lay_box + 3 * NCH * 6, feat, pooled);
    } else {
        sample_kernel<true, false><<<smpGrid, 512, 0, stream>>>(mixed, lay_geo + 3 * NCH * 6,
                                                                lay_box + 3 * NCH * 6, feat, pooled);
        pool_kernel<<<NB * NCH, 256, 0, stream>>>(feat, pooled);
    }
    dense_kernel<<<(NB * 1000 + 255) / 256, 256, 0, stream>>>(pooled, dense_w, dense_b, out);
}

// Round 3
// 585.855 us; speedup vs baseline: 1.1039x; 1.1039x over previous
//
#include <hip/hip_runtime.h>

#define HW 96
#define NPIX 9216      // 96*96
#define NCH 128
#define NB 16
#define HP 98          // haloed plane dim (coords -1..96)

// ---------------- channel mix: mixed[b,c,p] = sum_i lin[c,i] * x[b,i,p] ----------------
// No-LDS GEMM. Block = 512 thr (8 waves), wave = 16 ch (lin wave-uniform ->
// s_load into SGPRs, the 1 allowed SGPR operand of v_fma), thread = 3 px at
// lane/lane+64/lane+128 (three coalesced dword streams, shared vaddr + imm offsets).
// R7: tile = 192 px x 128 ch -> grid = 48*16 = 768 blocks = EXACTLY 3 blocks/CU,
// all resident in ONE round (24 waves/CU), no dispatch tail. R5/R6's 1152-block
// grid ran 1.125 rounds (1024 resident + 128-block tail at 12.5% util) -> Occ 43%,
// VALU 51%. __launch_bounds__(512,6) caps VGPR at 85 to guarantee 3 blocks/CU.
// R6 post-mortem: manual ping-pong double-buffer REGRESSED (92us, VALU 41%) --
// compiler already pipelines the simple loop; reverted to straight load+FMA body.
// R8: identical to R7 — R7's bench run died on container infrastructure, no data.
template<int K>
__global__ __launch_bounds__(512, 6) void mix_kernel(const float* __restrict__ x,
                                                     const float* __restrict__ lin,
                                                     float* __restrict__ mixed) {
    const int b    = blockIdx.y;
    const int lane = threadIdx.x & 63;
    const int p    = blockIdx.x * 192 + lane;     // pixels p, p+64, p+128
    const int c0   = __builtin_amdgcn_readfirstlane((threadIdx.x >> 6) * 16);
    const float* xb = x + (size_t)b * K * NPIX + p;
    const float* lr = lin + c0 * K;

    float acc[16][3];
    #pragma unroll
    for (int c = 0; c < 16; ++c) acc[c][0] = acc[c][1] = acc[c][2] = 0.f;

    for (int k0 = 0; k0 < K; k0 += 4) {
        float xv[4][3];
        #pragma unroll
        for (int j = 0; j < 4; ++j) {
            const float* xp = xb + (size_t)(k0 + j) * NPIX;
            xv[j][0] = xp[0];
            xv[j][1] = xp[64];
            xv[j][2] = xp[128];
        }
        #pragma unroll
        for (int c = 0; c < 16; ++c) {
            const float* lc = lr + c * K + k0;     // wave-uniform -> scalar loads
            #pragma unroll
            for (int j = 0; j < 4; ++j) {
                acc[c][0] = fmaf(lc[j], xv[j][0], acc[c][0]);
                acc[c][1] = fmaf(lc[j], xv[j][1], acc[c][1]);
                acc[c][2] = fmaf(lc[j], xv[j][2], acc[c][2]);
            }
        }
    }
    float* ob = mixed + (size_t)b * NCH * NPIX + p;
    #pragma unroll
    for (int c = 0; c < 16; ++c) {
        float* op = ob + (size_t)(c0 + c) * NPIX;
        op[0]   = acc[c][0];
        op[64]  = acc[c][1];
        op[128] = acc[c][2];
    }
}

__device__ inline float clamp01(float z) { return fminf(fmaxf(z, 0.f), 1.f); }

// ---------------- bilinear affine sample (zero-halo LDS plane) ----------------
// Plane staged into LDS with a 1px zero border (coords -1..96). ix clamped to
// [-1,96]: every out-of-range tap then reads a zero cell with the correct
// weight, eliminating all validity masks. Box-sample-of-ones factorizes:
// bw = min(clamp01(bx+1), clamp01(96-bx)) * (same in y). 2-lerp form = 6 FMA.
// 512 threads: LDS (38.4 KB) still allows 4 blocks/CU -> 32 waves/CU; grid
// 2048 = exactly 2 balanced rounds of 4 blocks/CU. (R6: 384->512 thr helped.)
template<bool RES, bool POOL>
__global__ __launch_bounds__(512) void sample_kernel(const float* __restrict__ mixed,
                                                     const float* __restrict__ geo,
                                                     const float* __restrict__ box,
                                                     float* __restrict__ out,
                                                     float* __restrict__ pooled) {
    __shared__ float m[HP * HP];           // 38.4 KB -> 4 blocks/CU, 32 waves/CU
    const int c = blockIdx.x;
    const int b = blockIdx.y;
    const int t = threadIdx.x;
    // zero only the halo border (interior is fully overwritten by the fill)
    if (t < HP) {                           // top & bottom rows
        m[t] = 0.f;
        m[(HP - 1) * HP + t] = 0.f;
    } else if (t < HP + 96) {               // left & right columns (rows 1..96)
        const int h = t - HP + 1;
        m[h * HP] = 0.f;
        m[h * HP + HP - 1] = 0.f;
    }
    const float* src = mixed + ((size_t)b * NCH + c) * NPIX;
    #pragma unroll
    for (int r = 0; r < NPIX / 512; ++r) {
        const int idx = r * 512 + t;
        const int h = idx / 96, w = idx - (idx / 96) * 96;
        m[(h + 1) * HP + (w + 1)] = src[idx];
    }
    const float* gth = geo + c * 6;
    const float* bth = box + c * 6;
    const float g0 = gth[0], g1 = gth[1], g3 = gth[3], g4 = gth[4];
    const float gcx = 48.f * gth[2] - 47.5f * (g0 + g1) + 47.5f;
    const float gcy = 48.f * gth[5] - 47.5f * (g3 + g4) + 47.5f;
    const float b0 = bth[0], b1 = bth[1], b3 = bth[3], b4 = bth[4];
    const float bcx = 48.f * bth[2] - 47.5f * (b0 + b1) + 47.5f;
    const float bcy = 48.f * bth[5] - 47.5f * (b3 + b4) + 47.5f;
    float* o = out + ((size_t)b * NCH + c) * NPIX;
    __syncthreads();
    float psum = 0.f;
    #pragma unroll 6
    for (int r = 0; r < NPIX / 512; ++r) {
        const int p = r * 512 + t;
        const int h = p / 96, w = p - (p / 96) * 96;
        const float fw = (float)w, fh = (float)h;
        float ix = fmaf(g0, fw, fmaf(g1, fh, gcx));
        float iy = fmaf(g3, fw, fmaf(g4, fh, gcy));
        ix = fminf(fmaxf(ix, -1.f), 96.f);
        iy = fminf(fmaxf(iy, -1.f), 96.f);
        const float x0f = floorf(ix), y0f = floorf(iy);
        const float fx = ix - x0f, fy = iy - y0f;
        const int base = ((int)y0f + 1) * HP + ((int)x0f + 1);
        const float m00 = m[base],      m01 = m[base + 1];
        const float m10 = m[base + HP], m11 = m[base + HP + 1];
        const float mx0 = fmaf(fx, m01 - m00, m00);
        const float mx1 = fmaf(fx, m11 - m10, m10);
        float v = fmaf(fy, mx1 - mx0, mx0);
        const float bx = fmaf(b0, fw, fmaf(b1, fh, bcx));
        const float by = fmaf(b3, fw, fmaf(b4, fh, bcy));
        const float Xs = fminf(clamp01(bx + 1.f), clamp01(96.f - bx));
        const float Ys = fminf(clamp01(by + 1.f), clamp01(96.f - by));
        v *= Xs * Ys;
        if (RES) v += o[p];
        o[p] = v;
        if (POOL) psum += v;
    }
    if (POOL) {
        #pragma unroll
        for (int off = 32; off > 0; off >>= 1) psum += __shfl_down(psum, off, 64);
        __shared__ float red[8];
        if ((t & 63) == 0) red[t >> 6] = psum;
        __syncthreads();
        if (t == 0) {
            float s = 0.f;
            #pragma unroll
            for (int i = 0; i < 8; ++i) s += red[i];
            pooled[b * NCH + c] = s * (1.f / (float)NPIX);
        }
    }
}

// ---------------- mean pool (fallback when ws has no room for pooled) ----------------
__global__ __launch_bounds__(256) void pool_kernel(const float* __restrict__ feat,
                                                   float* __restrict__ pooled) {
    const int bc = blockIdx.x;           // b*128 + c
    const float4* f = (const float4*)(feat + (size_t)bc * NPIX);
    float s = 0.f;
    for (int i = threadIdx.x; i < NPIX / 4; i += 256) {
        const float4 v = f[i];
        s += (v.x + v.y) + (v.z + v.w);
    }
    #pragma unroll
    for (int off = 32; off > 0; off >>= 1) s += __shfl_down(s, off, 64);
    __shared__ float red[4];
    if ((threadIdx.x & 63) == 0) red[threadIdx.x >> 6] = s;
    __syncthreads();
    if (threadIdx.x == 0)
        pooled[bc] = (red[0] + red[1] + red[2] + red[3]) * (1.f / (float)NPIX);
}

// ---------------- dense: logits[b,n] = pooled[b,:] . W[n,:] + bias[n] ----------------
__global__ __launch_bounds__(256) void dense_kernel(const float* __restrict__ pooled,
                                                    const float* __restrict__ Wt,
                                                    const float* __restrict__ bias,
                                                    float* __restrict__ out) {
    const int idx = blockIdx.x * 256 + threadIdx.x;
    if (idx >= NB * 1000) return;
    const int b = idx / 1000, n = idx - b * 1000;
    float acc = bias[n];
    const float* p = pooled + b * NCH;
    const float* wr = Wt + n * NCH;
    #pragma unroll 4
    for (int c = 0; c < NCH; ++c) acc = fmaf(p[c], wr[c], acc);
    out[idx] = acc;
}

extern "C" void kernel_launch(void* const* d_in, const int* in_sizes, int n_in,
                              void* d_out, int out_size, void* d_ws, size_t ws_size,
                              hipStream_t stream) {
    const float* x       = (const float*)d_in[0];   // [16,64,96,96]
    const float* in_geo  = (const float*)d_in[1];   // [128,2,3]
    const float* in_box  = (const float*)d_in[2];   // [128,2,3]
    const float* in_lin  = (const float*)d_in[3];   // [128,64]
    const float* lay_geo = (const float*)d_in[4];   // [4,128,2,3]
    const float* lay_box = (const float*)d_in[5];   // [4,128,2,3]
    const float* lay_lin = (const float*)d_in[6];   // [4,128,128]
    const float* dense_w = (const float*)d_in[7];   // [1000,128]
    const float* dense_b = (const float*)d_in[8];   // [1000]

    float* out  = (float*)d_out;
    float* feat = out + NB * 1000;                  // [16,128,96,96] lives in d_out
    float* mixed = (float*)d_ws;                    // 75.5 MB scratch

    const size_t mixedFloats = (size_t)NB * NCH * NPIX;
    const bool fusedPool = ws_size >= (mixedFloats + NB * NCH) * sizeof(float);
    float* pooled = fusedPool ? (float*)d_ws + mixedFloats : (float*)d_ws;

    const dim3 mixGrid(NPIX / 192, NB);             // 48 x 16 = 768 blocks = 3/CU, 1 round
    const dim3 smpGrid(NCH, NB);

    mix_kernel<64><<<mixGrid, 512, 0, stream>>>(x, in_lin, mixed);
    sample_kernel<false, false><<<smpGrid, 512, 0, stream>>>(mixed, in_geo, in_box, feat, pooled);
    for (int i = 0; i < 3; ++i) {
        mix_kernel<128><<<mixGrid, 512, 0, stream>>>(feat, lay_lin + i * NCH * NCH, mixed);
        sample_kernel<true, false><<<smpGrid, 512, 0, stream>>>(mixed, lay_geo + i * NCH * 6,
                                                                lay_box + i * NCH * 6, feat, pooled);
    }
    mix_kernel<128><<<mixGrid, 512, 0, stream>>>(feat, lay_lin + 3 * NCH * NCH, mixed);
    if (fusedPool) {
        sample_kernel<true, true><<<smpGrid, 512, 0, stream>>>(mixed, lay_geo + 3 * NCH * 6,
                                                               lay_box + 3 * NCH * 6, feat, pooled);
    } else {
        sample_kernel<true, false><<<smpGrid, 512, 0, stream>>>(mixed, lay_geo + 3 * NCH * 6,
                                                                lay_box + 3 * NCH * 6, feat, pooled);
        pool_kernel<<<NB * NCH, 256, 0, stream>>>(feat, pooled);
    }
    dense_kernel<<<(NB * 1000 + 255) / 256, 256, 0, stream>>>(pooled, dense_w, dense_b, out);
}